// Round 9
// baseline (350.710 us; speedup 1.0000x reference)
//
#include <hip/hip_runtime.h>
#include <hip/hip_bf16.h>

#define NN 100000
#define NE 800000
#define HD 128
#define BN_EPS 1e-5f
#define NB_E_C 3125   // (NE+255)/256
#define NB_G_C 1563   // (NN+63)/64

typedef __bf16 bf16x8 __attribute__((ext_vector_type(8)));
typedef float  f32x4  __attribute__((ext_vector_type(4)));
typedef float  f32x2  __attribute__((ext_vector_type(2)));

// ---------------- fused dispatch 0 ----------------
// blocks 0-1: transpose W1/W2 -> WT (bf16); block 2: BN affine precompute;
// blocks 3..3+NB_E_C: per-dst histogram + edge rank;
// remaining NB_G_C blocks: layer-0 GEMM (x fp32 @ W0 -> hw bf16), staging W0
// TRANSPOSED ON THE FLY (no dependency on the transpose blocks).
// Independent work overlaps inside one dispatch: the atomic histogram hides
// under the GEMM's streaming reads.

__global__ __launch_bounds__(256, 4) void fused0_k(const int* __restrict__ ei, int* __restrict__ count,
                                                   int* __restrict__ rank,
                                                   const float* __restrict__ x, const float* __restrict__ W0,
                                                   const float* __restrict__ W1, const float* __restrict__ W2,
                                                   __bf16* __restrict__ WT, __bf16* __restrict__ hw,
                                                   const float* __restrict__ g0, const float* __restrict__ b0,
                                                   const float* __restrict__ m0, const float* __restrict__ v0,
                                                   const float* __restrict__ g1, const float* __restrict__ b1,
                                                   const float* __restrict__ m1, const float* __restrict__ v1,
                                                   float* __restrict__ A0, float* __restrict__ B0,
                                                   float* __restrict__ A1, float* __restrict__ B1) {
    __shared__ __bf16 WL[128 * 128];   // used by the GEMM branch only
    const int bid = blockIdx.x;
    const int tid = threadIdx.x;

    if (bid < 2) {
        // transpose W1 (bid 0) / W2 (bid 1) -> WT slots 1,2
        const float* W = (bid == 0) ? W1 : W2;
        __bf16* T = WT + (bid + 1) * (HD * HD);
        #pragma unroll 4
        for (int it = 0; it < 64; ++it) {
            int idx = it * 256 + tid;          // idx = n*128 + k (writes coalesced)
            int n = idx >> 7, k = idx & 127;
            T[idx] = (__bf16)W[k * HD + n];
        }
        return;
    }
    if (bid == 2) {
        if (tid < 128) {
            float a = g0[tid] * rsqrtf(v0[tid] + BN_EPS);
            A0[tid] = a; B0[tid] = b0[tid] - m0[tid] * a;
        } else {
            int u = tid - 128;
            float a = g1[u] * rsqrtf(v1[u] + BN_EPS);
            A1[u] = a; B1[u] = b1[u] - m1[u] * a;
        }
        return;
    }
    if (bid < 3 + NB_E_C) {
        int e = (bid - 3) * 256 + tid;
        if (e < NE) rank[e] = atomicAdd(&count[ei[NE + e]], 1);
        return;
    }

    // ---- GEMM branch: 64 rows per block ----
    const int gb = bid - 3 - NB_E_C;
    const int wid  = __builtin_amdgcn_readfirstlane(tid >> 6);
    const int lane = tid & 63;
    const int m = lane & 15, quad = lane >> 4;
    const int row_base = gb * 64 + wid * 16;

    // prefetch this lane's 4 A-fragments (k = ks*32 + quad*8) before the barrier
    int r = row_base + m;
    if (r >= NN) r = NN - 1;
    bf16x8 afr[4];
    {
        const float4* ap = (const float4*)(x + (size_t)r * HD);
        #pragma unroll
        for (int ks = 0; ks < 4; ++ks) {
            float4 x0 = ap[ks * 8 + quad * 2], x1 = ap[ks * 8 + quad * 2 + 1];
            bf16x8 a;
            a[0] = (__bf16)x0.x; a[1] = (__bf16)x0.y; a[2] = (__bf16)x0.z; a[3] = (__bf16)x0.w;
            a[4] = (__bf16)x1.x; a[5] = (__bf16)x1.y; a[6] = (__bf16)x1.z; a[7] = (__bf16)x1.w;
            afr[ks] = a;
        }
    }

    // stage W0 -> LDS transposed on the fly (WL[n][k] = W0[k][n], bf16),
    // chunk-XOR swizzle: chunk c of row n lands at c^(n>>3). W0 is 64 KB,
    // L2-resident across all GEMM blocks.
    #pragma unroll
    for (int it = 0; it < 8; ++it) {
        int id = it * 256 + tid;          // chunk id
        int n = id >> 4, c = id & 15;     // row (out-channel), 16B-chunk (8 k's)
        int cs = c ^ (n >> 3);
        bf16x8 v;
        #pragma unroll
        for (int j = 0; j < 8; ++j) v[j] = (__bf16)W0[(c * 8 + j) * HD + n];
        *(bf16x8*)&WL[n * 128 + cs * 8] = v;
    }
    __syncthreads();

    f32x4 acc[8];
    #pragma unroll
    for (int ct = 0; ct < 8; ++ct) acc[ct] = (f32x4){0.f, 0.f, 0.f, 0.f};

    #pragma unroll
    for (int ks = 0; ks < 4; ++ks) {
        #pragma unroll
        for (int ct = 0; ct < 8; ++ct) {
            int n = m * 8 + ct;                       // channel fed to tile ct, col m
            int cs = (ks * 4 + quad) ^ m;             // swizzled 16B chunk (key = n>>3 = m)
            bf16x8 bfr = *(const bf16x8*)&WL[n * 128 + cs * 8];
            acc[ct] = __builtin_amdgcn_mfma_f32_16x16x32_bf16(afr[ks], bfr, acc[ct], 0, 0, 0);
        }
    }

    // coalesced epilogue: one bf16x8 (16B) store per lane per row
    #pragma unroll
    for (int rr = 0; rr < 4; ++rr) {
        int row = row_base + quad * 4 + rr;
        if (row < NN) {
            bf16x8 v;
            #pragma unroll
            for (int ct = 0; ct < 8; ++ct) v[ct] = (__bf16)acc[ct][rr];
            *(bf16x8*)(hw + (size_t)row * HD + m * 8) = v;
        }
    }
}

// block-level exclusive scan of count + per-node norm terms
__global__ __launch_bounds__(256) void scan1_k(const int* __restrict__ count,
                                               int* __restrict__ rp, int* __restrict__ bsums,
                                               float* __restrict__ dis, float* __restrict__ selfn) {
    __shared__ int sm[256];
    int tid = threadIdx.x;
    int i = blockIdx.x * 256 + tid;
    int v = (i < NN) ? count[i] : 0;
    if (i < NN) {
        float deg = (float)v + 1.0f;
        float di = rsqrtf(deg);
        dis[i] = di;
        selfn[i] = di * di;
    }
    sm[tid] = v; __syncthreads();
    for (int off = 1; off < 256; off <<= 1) {
        int t = (tid >= off) ? sm[tid - off] : 0;
        __syncthreads();
        sm[tid] += t;
        __syncthreads();
    }
    if (i < NN) rp[i] = sm[tid] - v;           // exclusive within block
    if (tid == 255) bsums[blockIdx.x] = sm[tid];
}

// fused scan2+scan3: every block redundantly reduces bsums[0..blockIdx)
__global__ __launch_bounds__(256) void scan23_k(int* __restrict__ rp, const int* __restrict__ bsums, int nb) {
    __shared__ int sm[256];
    int tid = threadIdx.x;
    int b = blockIdx.x;
    int partial = 0;
    for (int i = tid; i < b; i += 256) partial += bsums[i];
    sm[tid] = partial; __syncthreads();
    #pragma unroll
    for (int off = 128; off > 0; off >>= 1) {
        if (tid < off) sm[tid] += sm[tid + off];
        __syncthreads();
    }
    int prefix = sm[0];
    int i = b * 256 + tid;
    if (i < NN) rp[i] += prefix;
    if (i == 0) rp[NN] = NE;
}

// scatter edges into CSR as packed (src, weight_bits); no atomics (rank precomputed)
__global__ __launch_bounds__(256) void scatter_k(const int* __restrict__ ei, const int* __restrict__ rp,
                                                 const int* __restrict__ rank, const float* __restrict__ dis,
                                                 uint2* __restrict__ edges) {
    int e = blockIdx.x * 256 + threadIdx.x;
    if (e >= NE) return;
    int s = ei[e], d = ei[NE + e];
    int pos = rp[d] + rank[e];
    edges[pos] = make_uint2((unsigned)s, __float_as_uint(dis[s] * dis[d]));
}

// ---------------- helpers ----------------

__device__ __forceinline__ void acc8p(f32x2* acc, uint4 rv, float wt) {
    f32x2 w2 = {wt, wt};
    f32x2 x0 = {__uint_as_float(rv.x << 16), __uint_as_float(rv.x & 0xffff0000u)};
    f32x2 x1 = {__uint_as_float(rv.y << 16), __uint_as_float(rv.y & 0xffff0000u)};
    f32x2 x2 = {__uint_as_float(rv.z << 16), __uint_as_float(rv.z & 0xffff0000u)};
    f32x2 x3 = {__uint_as_float(rv.w << 16), __uint_as_float(rv.w & 0xffff0000u)};
    acc[0] = __builtin_elementwise_fma(x0, w2, acc[0]);
    acc[1] = __builtin_elementwise_fma(x1, w2, acc[1]);
    acc[2] = __builtin_elementwise_fma(x2, w2, acc[2]);
    acc[3] = __builtin_elementwise_fma(x3, w2, acc[3]);
}

__device__ __forceinline__ void unpack8(uint4 rv, float* f) {
    f[0] = __uint_as_float(rv.x << 16);         f[1] = __uint_as_float(rv.x & 0xffff0000u);
    f[2] = __uint_as_float(rv.y << 16);         f[3] = __uint_as_float(rv.y & 0xffff0000u);
    f[4] = __uint_as_float(rv.z << 16);         f[5] = __uint_as_float(rv.z & 0xffff0000u);
    f[6] = __uint_as_float(rv.w << 16);         f[7] = __uint_as_float(rv.w & 0xffff0000u);
}

// ---------------- layer-0 aggregation: hb = relu(agg(hw) + b0) ----------------
// 4 nodes per wave, 16 lanes per node, 4-deep pipelined gather.

__global__ __launch_bounds__(256) void agg0_k(const __bf16* __restrict__ hw, const int* __restrict__ rp,
                                              const uint2* __restrict__ edges,
                                              const float* __restrict__ selfn, const float* __restrict__ bias,
                                              __bf16* __restrict__ hb) {
    const int lane = threadIdx.x & 63;
    const int wid  = threadIdx.x >> 6;
    const int grp  = lane >> 4;
    const int m    = lane & 15;
    const int n = blockIdx.x * 16 + wid * 4 + grp;   // NN = 6250*16 exactly
    const int c0 = m * 8;
    const int L = NE - 1;

    const int e0 = rp[n], e1 = rp[n + 1];
    const float sn = selfn[n];
    uint4 rv_self = *(const uint4*)(hw + ((size_t)n << 7) + c0);

    f32x2 acc2[4];
    #pragma unroll
    for (int j = 0; j < 4; ++j) acc2[j] = (f32x2){0.f, 0.f};

    int e = e0;
    int cnt = e1 - e0;
    uint2 edA = edges[min(e,     L)];
    uint2 edB = edges[min(e + 1, L)];
    uint2 edC = edges[min(e + 2, L)];
    uint2 edD = edges[min(e + 3, L)];
    while (cnt >= 4) {
        uint4 r0 = *(const uint4*)(hw + ((size_t)edA.x << 7) + c0);
        uint4 r1 = *(const uint4*)(hw + ((size_t)edB.x << 7) + c0);
        uint4 r2 = *(const uint4*)(hw + ((size_t)edC.x << 7) + c0);
        uint4 r3 = *(const uint4*)(hw + ((size_t)edD.x << 7) + c0);
        uint2 nA = edges[min(e + 4, L)];
        uint2 nB = edges[min(e + 5, L)];
        uint2 nC = edges[min(e + 6, L)];
        uint2 nD = edges[min(e + 7, L)];
        acc8p(acc2, r0, __uint_as_float(edA.y));
        acc8p(acc2, r1, __uint_as_float(edB.y));
        acc8p(acc2, r2, __uint_as_float(edC.y));
        acc8p(acc2, r3, __uint_as_float(edD.y));
        edA = nA; edB = nB; edC = nC; edD = nD;
        e += 4; cnt -= 4;
    }
    if (cnt >= 2) {
        uint4 r0 = *(const uint4*)(hw + ((size_t)edA.x << 7) + c0);
        uint4 r1 = *(const uint4*)(hw + ((size_t)edB.x << 7) + c0);
        acc8p(acc2, r0, __uint_as_float(edA.y));
        acc8p(acc2, r1, __uint_as_float(edB.y));
        edA = edC;
        cnt -= 2;
    }
    if (cnt == 1) {
        uint4 rv = *(const uint4*)(hw + ((size_t)edA.x << 7) + c0);
        acc8p(acc2, rv, __uint_as_float(edA.y));
    }
    acc8p(acc2, rv_self, sn);

    float a8[8] = {acc2[0][0], acc2[0][1], acc2[1][0], acc2[1][1],
                   acc2[2][0], acc2[2][1], acc2[3][0], acc2[3][1]};
    float4 bs0 = *(const float4*)(bias + c0);
    float4 bs1 = *(const float4*)(bias + c0 + 4);
    float bf[8] = {bs0.x, bs0.y, bs0.z, bs0.w, bs1.x, bs1.y, bs1.z, bs1.w};
    bf16x8 v;
    #pragma unroll
    for (int j = 0; j < 8; ++j) v[j] = (__bf16)fmaxf(a8[j] + bf[j], 0.f);
    *(bf16x8*)(hb + ((size_t)n << 7) + c0) = v;
}

// ---------------- fused aggregation + weight multiply (layers 1,2) ----------------
// W staged once into LDS; barrier BEFORE the gather; wave-independent gather;
// A-row mapping row r <- node r>>2 so C row == own node, C col m == channels
// m*8+ct; s redistributed via __shfl; coalesced bf16x8 output store.
// __launch_bounds__(512,4): VGPR cap 128 (4-deep pipeline needs ~80; an
// 8-waves/EU bound spills ~88 MB — measured round 7).
// MODE 1: hbO = relu(bn(z)) + h; MODE 2: + in-register W3 projection -> hw3.

template <int MODE>
__global__ __launch_bounds__(512, 4) void aggw_k(const __bf16* __restrict__ hbI, const __bf16* __restrict__ WTg,
                                                 const int* __restrict__ rp, const uint2* __restrict__ edges,
                                                 const float* __restrict__ selfn, const float* __restrict__ bias,
                                                 const float* __restrict__ bnA, const float* __restrict__ bnB,
                                                 __bf16* __restrict__ hbO, const float* __restrict__ W3,
                                                 float2* __restrict__ hw3) {
    __shared__ __bf16 WLs[128 * 128];   // 32 KiB, staged W^T (read-only after barrier)
    const int tid = threadIdx.x;
    const int wid  = tid >> 6;          // 8 waves
    const int lane = tid & 63;
    const int grp  = lane >> 4;         // node within wave
    const int m    = lane & 15;         // channel chunk (channels 8m..8m+7)
    const int n = blockIdx.x * 32 + wid * 4 + grp;   // NN = 3125*32 exactly
    const int c0 = m * 8;
    const int L = NE - 1;

    // stage W^T -> LDS with chunk-XOR swizzle (key n>>3), then barrier BEFORE
    // the gather: uniform work, so the barrier couples nothing expensive.
    #pragma unroll
    for (int it = 0; it < 4; ++it) {
        int id = it * 512 + tid;
        int r = id >> 4, c = id & 15;
        int cs = c ^ (r >> 3);
        *(uint4*)&WLs[r * 128 + cs * 8] = *(const uint4*)(WTg + r * HD + c * 8);
    }
    __syncthreads();

    const int e0 = rp[n], e1 = rp[n + 1];
    const float sn = selfn[n];
    uint4 rv_self = *(const uint4*)(hbI + ((size_t)n << 7) + c0);

    f32x2 acc2[4];
    #pragma unroll
    for (int j = 0; j < 4; ++j) acc2[j] = (f32x2){0.f, 0.f};

    // 4-deep pipelined gather (identical to agg0)
    int e = e0;
    int cnt = e1 - e0;
    uint2 edA = edges[min(e,     L)];
    uint2 edB = edges[min(e + 1, L)];
    uint2 edC = edges[min(e + 2, L)];
    uint2 edD = edges[min(e + 3, L)];
    while (cnt >= 4) {
        uint4 r0 = *(const uint4*)(hbI + ((size_t)edA.x << 7) + c0);
        uint4 r1 = *(const uint4*)(hbI + ((size_t)edB.x << 7) + c0);
        uint4 r2 = *(const uint4*)(hbI + ((size_t)edC.x << 7) + c0);
        uint4 r3 = *(const uint4*)(hbI + ((size_t)edD.x << 7) + c0);
        uint2 nA = edges[min(e + 4, L)];
        uint2 nB = edges[min(e + 5, L)];
        uint2 nC = edges[min(e + 6, L)];
        uint2 nD = edges[min(e + 7, L)];
        acc8p(acc2, r0, __uint_as_float(edA.y));
        acc8p(acc2, r1, __uint_as_float(edB.y));
        acc8p(acc2, r2, __uint_as_float(edC.y));
        acc8p(acc2, r3, __uint_as_float(edD.y));
        edA = nA; edB = nB; edC = nC; edD = nD;
        e += 4; cnt -= 4;
    }
    if (cnt >= 2) {
        uint4 r0 = *(const uint4*)(hbI + ((size_t)edA.x << 7) + c0);
        uint4 r1 = *(const uint4*)(hbI + ((size_t)edB.x << 7) + c0);
        acc8p(acc2, r0, __uint_as_float(edA.y));
        acc8p(acc2, r1, __uint_as_float(edB.y));
        edA = edC;
        cnt -= 2;
    }
    if (cnt == 1) {
        uint4 rv = *(const uint4*)(hbI + ((size_t)edA.x << 7) + c0);
        acc8p(acc2, rv, __uint_as_float(edA.y));
    }
    acc8p(acc2, rv_self, sn);   // self-loop (pre-W, h-space)

    // s -> bf16 in registers
    float a8[8] = {acc2[0][0], acc2[0][1], acc2[1][0], acc2[1][1],
                   acc2[2][0], acc2[2][1], acc2[3][0], acc2[3][1]};
    bf16x8 sv;
    #pragma unroll
    for (int j = 0; j < 8; ++j) sv[j] = (__bf16)a8[j];

    // A-frags via in-register wave transpose: lane (m,grp) needs
    // s[node m>>2][k = ks*32 + grp*8 ..+7], held by lane (m>>2)*16 + ks*4 + grp.
    int4 svi = *(int4*)&sv;
    const int base = ((m >> 2) << 4) + grp;
    bf16x8 afr[4];
    #pragma unroll
    for (int ks = 0; ks < 4; ++ks) {
        int sl = base + ks * 4;
        int4 r;
        r.x = __shfl(svi.x, sl, 64);
        r.y = __shfl(svi.y, sl, 64);
        r.z = __shfl(svi.z, sl, 64);
        r.w = __shfl(svi.w, sl, 64);
        afr[ks] = *(bf16x8*)&r;
    }

    // per-lane epilogue tables (channels c0..c0+7)
    float4 bs0 = *(const float4*)(bias + c0);
    float4 bs1 = *(const float4*)(bias + c0 + 4);
    float4 a0v = *(const float4*)(bnA + c0), a1v = *(const float4*)(bnA + c0 + 4);
    float4 b0v = *(const float4*)(bnB + c0), b1v = *(const float4*)(bnB + c0 + 4);
    float bf[8] = {bs0.x, bs0.y, bs0.z, bs0.w, bs1.x, bs1.y, bs1.z, bs1.w};
    float Af[8] = {a0v.x, a0v.y, a0v.z, a0v.w, a1v.x, a1v.y, a1v.z, a1v.w};
    float Bf[8] = {b0v.x, b0v.y, b0v.z, b0v.w, b1v.x, b1v.y, b1v.z, b1v.w};
    float pr[8];
    unpack8(rv_self, pr);               // residual row (this lane's node+chunk)
    float w3f[16];
    if (MODE == 2) {
        const float4* wp3 = (const float4*)(W3 + m * 16);   // rows m*8..m*8+7
        #pragma unroll
        for (int j = 0; j < 4; ++j) {
            float4 t = wp3[j];
            w3f[j * 4] = t.x; w3f[j * 4 + 1] = t.y; w3f[j * 4 + 2] = t.z; w3f[j * 4 + 3] = t.w;
        }
    }

    // ct loop: channel m*8+ct; B from LDS; acc rows all duplicate node grp.
    float h8[8];
    #pragma unroll
    for (int ct = 0; ct < 8; ++ct) {
        const int nW = m * 8 + ct;
        f32x4 acc = (f32x4){0.f, 0.f, 0.f, 0.f};
        #pragma unroll
        for (int ks = 0; ks < 4; ++ks) {
            int cs = (ks * 4 + grp) ^ m;
            bf16x8 bfr = *(const bf16x8*)&WLs[nW * 128 + cs * 8];
            acc = __builtin_amdgcn_mfma_f32_16x16x32_bf16(afr[ks], bfr, acc, 0, 0, 0);
        }
        float z = acc[0] + bf[ct];
        h8[ct] = fmaxf(fmaf(z, Af[ct], Bf[ct]), 0.f) + pr[ct];
    }

    if (MODE == 1) {
        bf16x8 v;
        #pragma unroll
        for (int j = 0; j < 8; ++j) v[j] = (__bf16)h8[j];
        *(bf16x8*)(hbO + ((size_t)n << 7) + c0) = v;     // coalesced, own node
    } else {
        // W3 projection: partial over this lane's 8 channels, reduce over m
        float p0 = 0.f, p1 = 0.f;
        #pragma unroll
        for (int j = 0; j < 8; ++j) {
            p0 = fmaf(h8[j], w3f[2 * j], p0);
            p1 = fmaf(h8[j], w3f[2 * j + 1], p1);
        }
        #pragma unroll
        for (int o = 1; o < 16; o <<= 1) {
            p0 += __shfl_xor(p0, o);
            p1 += __shfl_xor(p1, o);
        }
        if (m == 0) hw3[n] = make_float2(p0, p1);
    }
}

// ---------------- final: aggregate hw3 + log_softmax ----------------

__global__ __launch_bounds__(256) void final_k(const float2* __restrict__ hw3, const int* __restrict__ rp,
                                               const uint2* __restrict__ edges,
                                               const float* __restrict__ selfn, const float* __restrict__ b3,
                                               float* __restrict__ out) {
    int n = blockIdx.x * 256 + threadIdx.x;
    if (n >= NN) return;
    const int L = NE - 1;
    float a0 = 0.f, a1 = 0.f;
    int e0 = rp[n], e1 = rp[n + 1];
    int cnt = e1 - e0;
    uint2 edA = edges[min(e0,     L)];
    uint2 edB = edges[min(e0 + 1, L)];
    int e = e0;
    while (cnt >= 2) {
        float2 v0 = hw3[edA.x];
        float2 v1 = hw3[edB.x];
        float w0 = __uint_as_float(edA.y), w1 = __uint_as_float(edB.y);
        edA = edges[min(e + 2, L)];
        edB = edges[min(e + 3, L)];
        a0 = fmaf(w0, v0.x, a0); a1 = fmaf(w0, v0.y, a1);
        a0 = fmaf(w1, v1.x, a0); a1 = fmaf(w1, v1.y, a1);
        e += 2; cnt -= 2;
    }
    if (cnt == 1) {
        float2 v = hw3[edA.x];
        float w = __uint_as_float(edA.y);
        a0 = fmaf(w, v.x, a0); a1 = fmaf(w, v.y, a1);
    }
    float sn = selfn[n];
    float2 hv = hw3[n];
    float z0 = a0 + sn * hv.x + b3[0];
    float z1 = a1 + sn * hv.y + b3[1];
    float mx = fmaxf(z0, z1);
    float l = mx + logf(expf(z0 - mx) + expf(z1 - mx));
    out[n * 2 + 0] = z0 - l;
    out[n * 2 + 1] = z1 - l;
}

// ---------------- launch ----------------

extern "C" void kernel_launch(void* const* d_in, const int* in_sizes, int n_in,
                              void* d_out, int out_size, void* d_ws, size_t ws_size,
                              hipStream_t stream) {
    (void)in_sizes; (void)n_in; (void)out_size; (void)ws_size;

    const float* x   = (const float*)d_in[0];
    const int*   ei  = (const int*)d_in[1];
    const float* W0  = (const float*)d_in[2];
    const float* b0  = (const float*)d_in[3];
    const float* W1  = (const float*)d_in[4];
    const float* b1  = (const float*)d_in[5];
    const float* W2  = (const float*)d_in[6];
    const float* b2  = (const float*)d_in[7];
    const float* W3  = (const float*)d_in[8];
    const float* b3  = (const float*)d_in[9];
    const float* bn0g = (const float*)d_in[10];
    const float* bn0b = (const float*)d_in[11];
    const float* bn0m = (const float*)d_in[12];
    const float* bn0v = (const float*)d_in[13];
    const float* bn1g = (const float*)d_in[14];
    const float* bn1b = (const float*)d_in[15];
    const float* bn1m = (const float*)d_in[16];
    const float* bn1v = (const float*)d_in[17];
    float* out = (float*)d_out;

    char* p = (char*)d_ws;
    auto alloc = [&](size_t bytes) -> void* {
        void* r = (void*)p;
        p += (bytes + 255) & ~(size_t)255;
        return r;
    };
    __bf16*  hb    = (__bf16*)alloc((size_t)NN * HD * 2);   // h after layer 0
    __bf16*  hb2   = (__bf16*)alloc((size_t)NN * HD * 2);   // h after layer 1
    __bf16*  hw    = (__bf16*)alloc((size_t)NN * HD * 2);   // x @ W0
    float2*  hw3   = (float2*)alloc((size_t)NN * 8);
    float*   dis   = (float*)alloc((size_t)NN * 4);
    float*   selfn = (float*)alloc((size_t)NN * 4);
    int*     count = (int*)alloc((size_t)NN * 4);
    int*     rp    = (int*)alloc((size_t)(NN + 1) * 4);
    uint2*   edges = (uint2*)alloc((size_t)NE * 8);
    int*     rank  = (int*)alloc((size_t)NE * 4);
    int*     bsums = (int*)alloc((size_t)512 * 4);
    float*   bnA0  = (float*)alloc(128 * 4);
    float*   bnB0  = (float*)alloc(128 * 4);
    float*   bnA1  = (float*)alloc(128 * 4);
    float*   bnB1  = (float*)alloc(128 * 4);
    __bf16*  WT    = (__bf16*)alloc((size_t)3 * HD * HD * 2);  // transposed bf16 weights (slots 1,2 used)

    const int NB_N = (NN + 255) / 256;   // 391
    const int NB_A = (NN + 15) / 16;     // 6250 (agg0: 16 nodes per block)
    const int NB_W = (NN + 31) / 32;     // 3125 (aggw: 32 nodes per 512-thr block)

    hipMemsetAsync(count, 0, (size_t)NN * 4, stream);

    // fused: W1/W2 transpose + BN precompute + edge histogram + layer-0 GEMM
    fused0_k<<<3 + NB_E_C + NB_G_C, 256, 0, stream>>>(ei, count, rank,
                                                      x, W0, W1, W2, WT, hw,
                                                      bn0g, bn0b, bn0m, bn0v,
                                                      bn1g, bn1b, bn1m, bn1v,
                                                      bnA0, bnB0, bnA1, bnB1);
    scan1_k<<<NB_N, 256, 0, stream>>>(count, rp, bsums, dis, selfn);
    scan23_k<<<NB_N, 256, 0, stream>>>(rp, bsums, NB_N);
    scatter_k<<<NB_E_C, 256, 0, stream>>>(ei, rp, rank, dis, edges);

    // layer 0 aggregation: hb = relu(agg(hw) + b0)
    agg0_k<<<NB_A, 256, 0, stream>>>(hw, rp, edges, selfn, b0, hb);
    // layer 1 (fused agg+W): hb2 = relu(bn0(agg(hb) @ W1 + b1)) + hb
    aggw_k<1><<<NB_W, 512, 0, stream>>>(hb, WT + HD * HD, rp, edges, selfn, b1,
                                        bnA0, bnB0, hb2, nullptr, nullptr);
    // layer 2 (fused agg+W+W3): hw3 = (relu(bn1(agg(hb2) @ W2 + b2)) + hb2) @ W3
    aggw_k<2><<<NB_W, 512, 0, stream>>>(hb2, WT + 2 * HD * HD, rp, edges, selfn, b2,
                                        bnA1, bnB1, nullptr, W3, hw3);
    // final aggregation + log_softmax
    final_k<<<NB_N, 256, 0, stream>>>(hw3, rp, edges, selfn, b3, out);
}

// Round 10
// 310.682 us; speedup vs baseline: 1.1288x; 1.1288x over previous
//
#include <hip/hip_runtime.h>
#include <hip/hip_bf16.h>

#define NN 100000
#define NE 800000
#define HD 128
#define BN_EPS 1e-5f
#define NB_E_C 3125   // (NE+255)/256
#define NB_G_C 1563   // (NN+63)/64

typedef __bf16 bf16x8 __attribute__((ext_vector_type(8)));
typedef float  f32x4  __attribute__((ext_vector_type(4)));
typedef float  f32x2  __attribute__((ext_vector_type(2)));

// ---------------- CSR build ----------------

// fused: histogram+rank (blocks 0..NB_E_C-1), weight transpose (3 blocks,
// coalesced WRITES, runs exactly once per W), BN affine precompute (1 block)
__global__ __launch_bounds__(256) void count_prep_k(const int* __restrict__ ei, int* __restrict__ count,
                                                    int* __restrict__ rank,
                                                    const float* __restrict__ W0, const float* __restrict__ W1,
                                                    const float* __restrict__ W2, __bf16* __restrict__ WT,
                                                    const float* __restrict__ g0, const float* __restrict__ b0,
                                                    const float* __restrict__ m0, const float* __restrict__ v0,
                                                    const float* __restrict__ g1, const float* __restrict__ b1,
                                                    const float* __restrict__ m1, const float* __restrict__ v1,
                                                    float* __restrict__ A0, float* __restrict__ B0,
                                                    float* __restrict__ A1, float* __restrict__ B1) {
    int bid = blockIdx.x;
    int tid = threadIdx.x;
    if (bid < NB_E_C) {
        int e = bid * 256 + tid;
        if (e < NE) rank[e] = atomicAdd(&count[ei[NE + e]], 1);
    } else if (bid < NB_E_C + 3) {
        int w = bid - NB_E_C;
        const float* Ws[3] = {W0, W1, W2};
        const float* W = Ws[w];
        __bf16* T = WT + w * (HD * HD);
        #pragma unroll 4
        for (int it = 0; it < 64; ++it) {
            int idx = it * 256 + tid;          // idx = n*128 + k (writes coalesced)
            int n = idx >> 7, k = idx & 127;
            T[idx] = (__bf16)W[k * HD + n];
        }
    } else {
        if (tid < 128) {
            float a = g0[tid] * rsqrtf(v0[tid] + BN_EPS);
            A0[tid] = a; B0[tid] = b0[tid] - m0[tid] * a;
        } else {
            int u = tid - 128;
            float a = g1[u] * rsqrtf(v1[u] + BN_EPS);
            A1[u] = a; B1[u] = b1[u] - m1[u] * a;
        }
    }
}

// block-level exclusive scan of count + per-node norm terms
__global__ __launch_bounds__(256) void scan1_k(const int* __restrict__ count,
                                               int* __restrict__ rp, int* __restrict__ bsums,
                                               float* __restrict__ dis, float* __restrict__ selfn) {
    __shared__ int sm[256];
    int tid = threadIdx.x;
    int i = blockIdx.x * 256 + tid;
    int v = (i < NN) ? count[i] : 0;
    if (i < NN) {
        float deg = (float)v + 1.0f;
        float di = rsqrtf(deg);
        dis[i] = di;
        selfn[i] = di * di;
    }
    sm[tid] = v; __syncthreads();
    for (int off = 1; off < 256; off <<= 1) {
        int t = (tid >= off) ? sm[tid - off] : 0;
        __syncthreads();
        sm[tid] += t;
        __syncthreads();
    }
    if (i < NN) rp[i] = sm[tid] - v;           // exclusive within block
    if (tid == 255) bsums[blockIdx.x] = sm[tid];
}

// fused scan2+scan3: every block redundantly reduces bsums[0..blockIdx)
__global__ __launch_bounds__(256) void scan23_k(int* __restrict__ rp, const int* __restrict__ bsums, int nb) {
    __shared__ int sm[256];
    int tid = threadIdx.x;
    int b = blockIdx.x;
    int partial = 0;
    for (int i = tid; i < b; i += 256) partial += bsums[i];
    sm[tid] = partial; __syncthreads();
    #pragma unroll
    for (int off = 128; off > 0; off >>= 1) {
        if (tid < off) sm[tid] += sm[tid + off];
        __syncthreads();
    }
    int prefix = sm[0];
    int i = b * 256 + tid;
    if (i < NN) rp[i] += prefix;
    if (i == 0) rp[NN] = NE;
}

// ---------------- fused scatter + layer-0 GEMM ----------------
// Both branches are ready after scan23 and fully independent:
// blocks 0..NB_E_C-1: scatter edges into CSR (random 8B writes);
// blocks NB_E_C..   : layer-0 GEMM (x fp32 @ WT[0] -> hw bf16) with the
// proven coalesced LDS staging (WT pre-transposed by count_prep_k).
// The random scatter hides under the GEMM's streaming MFMA work.

__global__ __launch_bounds__(256, 5) void scatter_gemm_k(const int* __restrict__ ei, const int* __restrict__ rp,
                                                         const int* __restrict__ rank, const float* __restrict__ dis,
                                                         uint2* __restrict__ edges,
                                                         const float* __restrict__ x, const __bf16* __restrict__ WTg,
                                                         __bf16* __restrict__ HW) {
    __shared__ __bf16 WL[128 * 128];   // GEMM branch only (32 KiB)
    const int bid = blockIdx.x;
    const int tid = threadIdx.x;

    if (bid < NB_E_C) {
        int e = bid * 256 + tid;
        if (e >= NE) return;
        int s = ei[e], d = ei[NE + e];
        int pos = rp[d] + rank[e];
        edges[pos] = make_uint2((unsigned)s, __float_as_uint(dis[s] * dis[d]));
        return;
    }

    // ---- GEMM branch: 64 rows per block, column-permuted B mapping ----
    const int gb = bid - NB_E_C;
    const int wid  = __builtin_amdgcn_readfirstlane(tid >> 6);
    const int lane = tid & 63;
    const int m = lane & 15, quad = lane >> 4;
    const int row_base = gb * 64 + wid * 16;

    // prefetch this lane's 4 A-fragments (k = ks*32 + quad*8) before the barrier
    int r = row_base + m;
    if (r >= NN) r = NN - 1;
    bf16x8 afr[4];
    {
        const float4* ap = (const float4*)(x + (size_t)r * HD);
        #pragma unroll
        for (int ks = 0; ks < 4; ++ks) {
            float4 x0 = ap[ks * 8 + quad * 2], x1 = ap[ks * 8 + quad * 2 + 1];
            bf16x8 a;
            a[0] = (__bf16)x0.x; a[1] = (__bf16)x0.y; a[2] = (__bf16)x0.z; a[3] = (__bf16)x0.w;
            a[4] = (__bf16)x1.x; a[5] = (__bf16)x1.y; a[6] = (__bf16)x1.z; a[7] = (__bf16)x1.w;
            afr[ks] = a;
        }
    }

    // stage WT -> LDS (coalesced 16B loads) with chunk-XOR swizzle c^(n>>3)
    #pragma unroll
    for (int it = 0; it < 8; ++it) {
        int id = it * 256 + tid;          // chunk id
        int n = id >> 4, c = id & 15;     // row, 16B-chunk within row
        int cs = c ^ (n >> 3);
        *(uint4*)&WL[n * 128 + cs * 8] = *(const uint4*)(WTg + n * HD + c * 8);
    }
    __syncthreads();

    f32x4 acc[8];
    #pragma unroll
    for (int ct = 0; ct < 8; ++ct) acc[ct] = (f32x4){0.f, 0.f, 0.f, 0.f};

    #pragma unroll
    for (int ks = 0; ks < 4; ++ks) {
        #pragma unroll
        for (int ct = 0; ct < 8; ++ct) {
            int n = m * 8 + ct;                       // channel fed to tile ct, col m
            int cs = (ks * 4 + quad) ^ m;             // swizzled 16B chunk (key = n>>3 = m)
            bf16x8 bfr = *(const bf16x8*)&WL[n * 128 + cs * 8];
            acc[ct] = __builtin_amdgcn_mfma_f32_16x16x32_bf16(afr[ks], bfr, acc[ct], 0, 0, 0);
        }
    }

    // coalesced epilogue: one bf16x8 (16B) store per lane per row
    #pragma unroll
    for (int rr = 0; rr < 4; ++rr) {
        int row = row_base + quad * 4 + rr;
        if (row < NN) {
            bf16x8 v;
            #pragma unroll
            for (int ct = 0; ct < 8; ++ct) v[ct] = (__bf16)acc[ct][rr];
            *(bf16x8*)(HW + (size_t)row * HD + m * 8) = v;
        }
    }
}

// ---------------- helpers ----------------

__device__ __forceinline__ void acc8p(f32x2* acc, uint4 rv, float wt) {
    f32x2 w2 = {wt, wt};
    f32x2 x0 = {__uint_as_float(rv.x << 16), __uint_as_float(rv.x & 0xffff0000u)};
    f32x2 x1 = {__uint_as_float(rv.y << 16), __uint_as_float(rv.y & 0xffff0000u)};
    f32x2 x2 = {__uint_as_float(rv.z << 16), __uint_as_float(rv.z & 0xffff0000u)};
    f32x2 x3 = {__uint_as_float(rv.w << 16), __uint_as_float(rv.w & 0xffff0000u)};
    acc[0] = __builtin_elementwise_fma(x0, w2, acc[0]);
    acc[1] = __builtin_elementwise_fma(x1, w2, acc[1]);
    acc[2] = __builtin_elementwise_fma(x2, w2, acc[2]);
    acc[3] = __builtin_elementwise_fma(x3, w2, acc[3]);
}

__device__ __forceinline__ void unpack8(uint4 rv, float* f) {
    f[0] = __uint_as_float(rv.x << 16);         f[1] = __uint_as_float(rv.x & 0xffff0000u);
    f[2] = __uint_as_float(rv.y << 16);         f[3] = __uint_as_float(rv.y & 0xffff0000u);
    f[4] = __uint_as_float(rv.z << 16);         f[5] = __uint_as_float(rv.z & 0xffff0000u);
    f[6] = __uint_as_float(rv.w << 16);         f[7] = __uint_as_float(rv.w & 0xffff0000u);
}

// ---------------- layer-0 aggregation: hb = relu(agg(hw) + b0) ----------------
// 4 nodes per wave, 16 lanes per node, 4-deep pipelined gather.

__global__ __launch_bounds__(256) void agg0_k(const __bf16* __restrict__ hw, const int* __restrict__ rp,
                                              const uint2* __restrict__ edges,
                                              const float* __restrict__ selfn, const float* __restrict__ bias,
                                              __bf16* __restrict__ hb) {
    const int lane = threadIdx.x & 63;
    const int wid  = threadIdx.x >> 6;
    const int grp  = lane >> 4;
    const int m    = lane & 15;
    const int n = blockIdx.x * 16 + wid * 4 + grp;   // NN = 6250*16 exactly
    const int c0 = m * 8;
    const int L = NE - 1;

    const int e0 = rp[n], e1 = rp[n + 1];
    const float sn = selfn[n];
    uint4 rv_self = *(const uint4*)(hw + ((size_t)n << 7) + c0);

    f32x2 acc2[4];
    #pragma unroll
    for (int j = 0; j < 4; ++j) acc2[j] = (f32x2){0.f, 0.f};

    int e = e0;
    int cnt = e1 - e0;
    uint2 edA = edges[min(e,     L)];
    uint2 edB = edges[min(e + 1, L)];
    uint2 edC = edges[min(e + 2, L)];
    uint2 edD = edges[min(e + 3, L)];
    while (cnt >= 4) {
        uint4 r0 = *(const uint4*)(hw + ((size_t)edA.x << 7) + c0);
        uint4 r1 = *(const uint4*)(hw + ((size_t)edB.x << 7) + c0);
        uint4 r2 = *(const uint4*)(hw + ((size_t)edC.x << 7) + c0);
        uint4 r3 = *(const uint4*)(hw + ((size_t)edD.x << 7) + c0);
        uint2 nA = edges[min(e + 4, L)];
        uint2 nB = edges[min(e + 5, L)];
        uint2 nC = edges[min(e + 6, L)];
        uint2 nD = edges[min(e + 7, L)];
        acc8p(acc2, r0, __uint_as_float(edA.y));
        acc8p(acc2, r1, __uint_as_float(edB.y));
        acc8p(acc2, r2, __uint_as_float(edC.y));
        acc8p(acc2, r3, __uint_as_float(edD.y));
        edA = nA; edB = nB; edC = nC; edD = nD;
        e += 4; cnt -= 4;
    }
    if (cnt >= 2) {
        uint4 r0 = *(const uint4*)(hw + ((size_t)edA.x << 7) + c0);
        uint4 r1 = *(const uint4*)(hw + ((size_t)edB.x << 7) + c0);
        acc8p(acc2, r0, __uint_as_float(edA.y));
        acc8p(acc2, r1, __uint_as_float(edB.y));
        edA = edC;
        cnt -= 2;
    }
    if (cnt == 1) {
        uint4 rv = *(const uint4*)(hw + ((size_t)edA.x << 7) + c0);
        acc8p(acc2, rv, __uint_as_float(edA.y));
    }
    acc8p(acc2, rv_self, sn);

    float a8[8] = {acc2[0][0], acc2[0][1], acc2[1][0], acc2[1][1],
                   acc2[2][0], acc2[2][1], acc2[3][0], acc2[3][1]};
    float4 bs0 = *(const float4*)(bias + c0);
    float4 bs1 = *(const float4*)(bias + c0 + 4);
    float bf[8] = {bs0.x, bs0.y, bs0.z, bs0.w, bs1.x, bs1.y, bs1.z, bs1.w};
    bf16x8 v;
    #pragma unroll
    for (int j = 0; j < 8; ++j) v[j] = (__bf16)fmaxf(a8[j] + bf[j], 0.f);
    *(bf16x8*)(hb + ((size_t)n << 7) + c0) = v;
}

// ---------------- fused aggregation + weight multiply (layers 1,2) ----------------
// W staged once into LDS; barrier BEFORE the gather; wave-independent gather;
// A-row mapping row r <- node r>>2 so C row == own node, C col m == channels
// m*8+ct; s redistributed via __shfl; coalesced bf16x8 output store.
// __launch_bounds__(512,4): VGPR cap 128 (4-deep pipeline needs ~80; an
// 8-waves/EU bound spills ~88 MB — measured round 7).
// MODE 1: hbO = relu(bn(z)) + h; MODE 2: + in-register W3 projection -> hw3.

template <int MODE>
__global__ __launch_bounds__(512, 4) void aggw_k(const __bf16* __restrict__ hbI, const __bf16* __restrict__ WTg,
                                                 const int* __restrict__ rp, const uint2* __restrict__ edges,
                                                 const float* __restrict__ selfn, const float* __restrict__ bias,
                                                 const float* __restrict__ bnA, const float* __restrict__ bnB,
                                                 __bf16* __restrict__ hbO, const float* __restrict__ W3,
                                                 float2* __restrict__ hw3) {
    __shared__ __bf16 WLs[128 * 128];   // 32 KiB, staged W^T (read-only after barrier)
    const int tid = threadIdx.x;
    const int wid  = tid >> 6;          // 8 waves
    const int lane = tid & 63;
    const int grp  = lane >> 4;         // node within wave
    const int m    = lane & 15;         // channel chunk (channels 8m..8m+7)
    const int n = blockIdx.x * 32 + wid * 4 + grp;   // NN = 3125*32 exactly
    const int c0 = m * 8;
    const int L = NE - 1;

    // stage W^T -> LDS with chunk-XOR swizzle (key n>>3), then barrier BEFORE
    // the gather: uniform work, so the barrier couples nothing expensive.
    #pragma unroll
    for (int it = 0; it < 4; ++it) {
        int id = it * 512 + tid;
        int r = id >> 4, c = id & 15;
        int cs = c ^ (r >> 3);
        *(uint4*)&WLs[r * 128 + cs * 8] = *(const uint4*)(WTg + r * HD + c * 8);
    }
    __syncthreads();

    const int e0 = rp[n], e1 = rp[n + 1];
    const float sn = selfn[n];
    uint4 rv_self = *(const uint4*)(hbI + ((size_t)n << 7) + c0);

    f32x2 acc2[4];
    #pragma unroll
    for (int j = 0; j < 4; ++j) acc2[j] = (f32x2){0.f, 0.f};

    // 4-deep pipelined gather (identical to agg0)
    int e = e0;
    int cnt = e1 - e0;
    uint2 edA = edges[min(e,     L)];
    uint2 edB = edges[min(e + 1, L)];
    uint2 edC = edges[min(e + 2, L)];
    uint2 edD = edges[min(e + 3, L)];
    while (cnt >= 4) {
        uint4 r0 = *(const uint4*)(hbI + ((size_t)edA.x << 7) + c0);
        uint4 r1 = *(const uint4*)(hbI + ((size_t)edB.x << 7) + c0);
        uint4 r2 = *(const uint4*)(hbI + ((size_t)edC.x << 7) + c0);
        uint4 r3 = *(const uint4*)(hbI + ((size_t)edD.x << 7) + c0);
        uint2 nA = edges[min(e + 4, L)];
        uint2 nB = edges[min(e + 5, L)];
        uint2 nC = edges[min(e + 6, L)];
        uint2 nD = edges[min(e + 7, L)];
        acc8p(acc2, r0, __uint_as_float(edA.y));
        acc8p(acc2, r1, __uint_as_float(edB.y));
        acc8p(acc2, r2, __uint_as_float(edC.y));
        acc8p(acc2, r3, __uint_as_float(edD.y));
        edA = nA; edB = nB; edC = nC; edD = nD;
        e += 4; cnt -= 4;
    }
    if (cnt >= 2) {
        uint4 r0 = *(const uint4*)(hbI + ((size_t)edA.x << 7) + c0);
        uint4 r1 = *(const uint4*)(hbI + ((size_t)edB.x << 7) + c0);
        acc8p(acc2, r0, __uint_as_float(edA.y));
        acc8p(acc2, r1, __uint_as_float(edB.y));
        edA = edC;
        cnt -= 2;
    }
    if (cnt == 1) {
        uint4 rv = *(const uint4*)(hbI + ((size_t)edA.x << 7) + c0);
        acc8p(acc2, rv, __uint_as_float(edA.y));
    }
    acc8p(acc2, rv_self, sn);   // self-loop (pre-W, h-space)

    // s -> bf16 in registers
    float a8[8] = {acc2[0][0], acc2[0][1], acc2[1][0], acc2[1][1],
                   acc2[2][0], acc2[2][1], acc2[3][0], acc2[3][1]};
    bf16x8 sv;
    #pragma unroll
    for (int j = 0; j < 8; ++j) sv[j] = (__bf16)a8[j];

    // A-frags via in-register wave transpose: lane (m,grp) needs
    // s[node m>>2][k = ks*32 + grp*8 ..+7], held by lane (m>>2)*16 + ks*4 + grp.
    int4 svi = *(int4*)&sv;
    const int base = ((m >> 2) << 4) + grp;
    bf16x8 afr[4];
    #pragma unroll
    for (int ks = 0; ks < 4; ++ks) {
        int sl = base + ks * 4;
        int4 r;
        r.x = __shfl(svi.x, sl, 64);
        r.y = __shfl(svi.y, sl, 64);
        r.z = __shfl(svi.z, sl, 64);
        r.w = __shfl(svi.w, sl, 64);
        afr[ks] = *(bf16x8*)&r;
    }

    // per-lane epilogue tables (channels c0..c0+7)
    float4 bs0 = *(const float4*)(bias + c0);
    float4 bs1 = *(const float4*)(bias + c0 + 4);
    float4 a0v = *(const float4*)(bnA + c0), a1v = *(const float4*)(bnA + c0 + 4);
    float4 b0v = *(const float4*)(bnB + c0), b1v = *(const float4*)(bnB + c0 + 4);
    float bf[8] = {bs0.x, bs0.y, bs0.z, bs0.w, bs1.x, bs1.y, bs1.z, bs1.w};
    float Af[8] = {a0v.x, a0v.y, a0v.z, a0v.w, a1v.x, a1v.y, a1v.z, a1v.w};
    float Bf[8] = {b0v.x, b0v.y, b0v.z, b0v.w, b1v.x, b1v.y, b1v.z, b1v.w};
    float pr[8];
    unpack8(rv_self, pr);               // residual row (this lane's node+chunk)
    float w3f[16];
    if (MODE == 2) {
        const float4* wp3 = (const float4*)(W3 + m * 16);   // rows m*8..m*8+7
        #pragma unroll
        for (int j = 0; j < 4; ++j) {
            float4 t = wp3[j];
            w3f[j * 4] = t.x; w3f[j * 4 + 1] = t.y; w3f[j * 4 + 2] = t.z; w3f[j * 4 + 3] = t.w;
        }
    }

    // ct loop: channel m*8+ct; B from LDS; acc rows all duplicate node grp.
    float h8[8];
    #pragma unroll
    for (int ct = 0; ct < 8; ++ct) {
        const int nW = m * 8 + ct;
        f32x4 acc = (f32x4){0.f, 0.f, 0.f, 0.f};
        #pragma unroll
        for (int ks = 0; ks < 4; ++ks) {
            int cs = (ks * 4 + grp) ^ m;
            bf16x8 bfr = *(const bf16x8*)&WLs[nW * 128 + cs * 8];
            acc = __builtin_amdgcn_mfma_f32_16x16x32_bf16(afr[ks], bfr, acc, 0, 0, 0);
        }
        float z = acc[0] + bf[ct];
        h8[ct] = fmaxf(fmaf(z, Af[ct], Bf[ct]), 0.f) + pr[ct];
    }

    if (MODE == 1) {
        bf16x8 v;
        #pragma unroll
        for (int j = 0; j < 8; ++j) v[j] = (__bf16)h8[j];
        *(bf16x8*)(hbO + ((size_t)n << 7) + c0) = v;     // coalesced, own node
    } else {
        // W3 projection: partial over this lane's 8 channels, reduce over m
        float p0 = 0.f, p1 = 0.f;
        #pragma unroll
        for (int j = 0; j < 8; ++j) {
            p0 = fmaf(h8[j], w3f[2 * j], p0);
            p1 = fmaf(h8[j], w3f[2 * j + 1], p1);
        }
        #pragma unroll
        for (int o = 1; o < 16; o <<= 1) {
            p0 += __shfl_xor(p0, o);
            p1 += __shfl_xor(p1, o);
        }
        if (m == 0) hw3[n] = make_float2(p0, p1);
    }
}

// ---------------- final: aggregate hw3 + log_softmax ----------------

__global__ __launch_bounds__(256) void final_k(const float2* __restrict__ hw3, const int* __restrict__ rp,
                                               const uint2* __restrict__ edges,
                                               const float* __restrict__ selfn, const float* __restrict__ b3,
                                               float* __restrict__ out) {
    int n = blockIdx.x * 256 + threadIdx.x;
    if (n >= NN) return;
    const int L = NE - 1;
    float a0 = 0.f, a1 = 0.f;
    int e0 = rp[n], e1 = rp[n + 1];
    int cnt = e1 - e0;
    uint2 edA = edges[min(e0,     L)];
    uint2 edB = edges[min(e0 + 1, L)];
    int e = e0;
    while (cnt >= 2) {
        float2 v0 = hw3[edA.x];
        float2 v1 = hw3[edB.x];
        float w0 = __uint_as_float(edA.y), w1 = __uint_as_float(edB.y);
        edA = edges[min(e + 2, L)];
        edB = edges[min(e + 3, L)];
        a0 = fmaf(w0, v0.x, a0); a1 = fmaf(w0, v0.y, a1);
        a0 = fmaf(w1, v1.x, a0); a1 = fmaf(w1, v1.y, a1);
        e += 2; cnt -= 2;
    }
    if (cnt == 1) {
        float2 v = hw3[edA.x];
        float w = __uint_as_float(edA.y);
        a0 = fmaf(w, v.x, a0); a1 = fmaf(w, v.y, a1);
    }
    float sn = selfn[n];
    float2 hv = hw3[n];
    float z0 = a0 + sn * hv.x + b3[0];
    float z1 = a1 + sn * hv.y + b3[1];
    float mx = fmaxf(z0, z1);
    float l = mx + logf(expf(z0 - mx) + expf(z1 - mx));
    out[n * 2 + 0] = z0 - l;
    out[n * 2 + 1] = z1 - l;
}

// ---------------- launch ----------------

extern "C" void kernel_launch(void* const* d_in, const int* in_sizes, int n_in,
                              void* d_out, int out_size, void* d_ws, size_t ws_size,
                              hipStream_t stream) {
    (void)in_sizes; (void)n_in; (void)out_size; (void)ws_size;

    const float* x   = (const float*)d_in[0];
    const int*   ei  = (const int*)d_in[1];
    const float* W0  = (const float*)d_in[2];
    const float* b0  = (const float*)d_in[3];
    const float* W1  = (const float*)d_in[4];
    const float* b1  = (const float*)d_in[5];
    const float* W2  = (const float*)d_in[6];
    const float* b2  = (const float*)d_in[7];
    const float* W3  = (const float*)d_in[8];
    const float* b3  = (const float*)d_in[9];
    const float* bn0g = (const float*)d_in[10];
    const float* bn0b = (const float*)d_in[11];
    const float* bn0m = (const float*)d_in[12];
    const float* bn0v = (const float*)d_in[13];
    const float* bn1g = (const float*)d_in[14];
    const float* bn1b = (const float*)d_in[15];
    const float* bn1m = (const float*)d_in[16];
    const float* bn1v = (const float*)d_in[17];
    float* out = (float*)d_out;

    char* p = (char*)d_ws;
    auto alloc = [&](size_t bytes) -> void* {
        void* r = (void*)p;
        p += (bytes + 255) & ~(size_t)255;
        return r;
    };
    __bf16*  hb    = (__bf16*)alloc((size_t)NN * HD * 2);   // h after layer 0
    __bf16*  hb2   = (__bf16*)alloc((size_t)NN * HD * 2);   // h after layer 1
    __bf16*  hw    = (__bf16*)alloc((size_t)NN * HD * 2);   // x @ W0
    float2*  hw3   = (float2*)alloc((size_t)NN * 8);
    float*   dis   = (float*)alloc((size_t)NN * 4);
    float*   selfn = (float*)alloc((size_t)NN * 4);
    int*     count = (int*)alloc((size_t)NN * 4);
    int*     rp    = (int*)alloc((size_t)(NN + 1) * 4);
    uint2*   edges = (uint2*)alloc((size_t)NE * 8);
    int*     rank  = (int*)alloc((size_t)NE * 4);
    int*     bsums = (int*)alloc((size_t)512 * 4);
    float*   bnA0  = (float*)alloc(128 * 4);
    float*   bnB0  = (float*)alloc(128 * 4);
    float*   bnA1  = (float*)alloc(128 * 4);
    float*   bnB1  = (float*)alloc(128 * 4);
    __bf16*  WT    = (__bf16*)alloc((size_t)3 * HD * HD * 2);  // transposed bf16 weights

    const int NB_N = (NN + 255) / 256;   // 391
    const int NB_A = (NN + 15) / 16;     // 6250 (agg0: 16 nodes per block)
    const int NB_W = (NN + 31) / 32;     // 3125 (aggw: 32 nodes per 512-thr block)

    hipMemsetAsync(count, 0, (size_t)NN * 4, stream);

    count_prep_k<<<NB_E_C + 4, 256, 0, stream>>>(ei, count, rank,
                                                 W0, W1, W2, WT,
                                                 bn0g, bn0b, bn0m, bn0v, bn1g, bn1b, bn1m, bn1v,
                                                 bnA0, bnB0, bnA1, bnB1);
    scan1_k<<<NB_N, 256, 0, stream>>>(count, rp, bsums, dis, selfn);
    scan23_k<<<NB_N, 256, 0, stream>>>(rp, bsums, NB_N);

    // fused: scatter (random writes) + layer-0 GEMM (streaming MFMA) —
    // independent work, one dispatch, mutual latency hiding
    scatter_gemm_k<<<NB_E_C + NB_G_C, 256, 0, stream>>>(ei, rp, rank, dis, edges,
                                                        x, WT, hw);

    // layer 0 aggregation: hb = relu(agg(hw) + b0)
    agg0_k<<<NB_A, 256, 0, stream>>>(hw, rp, edges, selfn, b0, hb);
    // layer 1 (fused agg+W): hb2 = relu(bn0(agg(hb) @ W1 + b1)) + hb
    aggw_k<1><<<NB_W, 512, 0, stream>>>(hb, WT + HD * HD, rp, edges, selfn, b1,
                                        bnA0, bnB0, hb2, nullptr, nullptr);
    // layer 2 (fused agg+W+W3): hw3 = (relu(bn1(agg(hb2) @ W2 + b2)) + hb2) @ W3
    aggw_k<2><<<NB_W, 512, 0, stream>>>(hb2, WT + 2 * HD * HD, rp, edges, selfn, b2,
                                        bnA1, bnB1, nullptr, W3, hw3);
    // final aggregation + log_softmax
    final_k<<<NB_N, 256, 0, stream>>>(hw3, rp, edges, selfn, b3, out);
}